// Round 8
// baseline (122.802 us; speedup 1.0000x reference)
//
#include <hip/hip_runtime.h>
#include <hip/hip_fp16.h>

// PairwiseMamba: 2304 independent mamba scans (T=1024, d_inner=4, d_state=8).
// R7: 512-thr blocks (8 waves), one sequence per block split into 16 segments
// of 64 steps: wave w's half h owns segment g=2w+h. LDS 33.8KB -> 4 blocks/CU
// = exactly 32 waves/CU; 9-block/CU supply drains in fine-grained ~1us block
// rounds (no cap-boundary straggler as in R6's 9-vs-8).
// launch_bounds(512,4): empirical compiler VGPR budget ~256/min_waves
// (granule 8) -> cap 64, the no-spill regime (R5/R6: 44-52 used; R2's 12MB
// scratch was lb(512,6)->40).
// Staging per (wave,half), all HW-coalesced contiguous writes (0 conflicts
// measured R4/R6): DT[t][d] float4, DS[t][d] uint4 half2(dtx,sz),
// BC[s][t] b32 stride 33; scan reads are b32 broadcasts on disjoint banks.
// Pointwise: conv folded into in_proj (v = alpha*c0m+beta*c1m+gamma*c0+
// delta*c1+cb) as pk_fma pairs.

typedef float v2f __attribute__((ext_vector_type(2)));

#define TT 1024
#define TC 32
#define NSEGS 16
#define SEGLEN (TT / NSEGS)            // 64
#define NCHUNK (SEGLEN / TC)           // 2
#define NUM_PAIRS 36
#define NSEQ 2304

// per-(wave,half) staging layout (float/uint slots):
// DT [0,128) floats, DS [128,256) uints, BC [256,520) uints
#define DT_OFF 0
#define DS_OFF 128
#define BC_OFF 256
#define BC_STRIDE 33                   // half2 slots per BC row (bank spread)
#define PER_HALF_STRIDE 528            // floats; %32==16 -> halves bank-disjoint
#define PER_WAVE (2 * PER_HALF_STRIDE) // 1056 floats
#define STAGE_TOTAL (8 * PER_WAVE)     // 8448 floats = 33792 B

__device__ __forceinline__ float fast_silu(float v) {
    float e = __builtin_amdgcn_exp2f(v * -1.4426950408889634f);
    return v * __builtin_amdgcn_rcpf(1.0f + e);
}
// softplus, direct form: log(1+exp(v)). Safe: |v| <~ 20 here.
__device__ __forceinline__ float fast_softplus(float v) {
    float e = __builtin_amdgcn_exp2f(v * 1.4426950408889634f);
    return __builtin_amdgcn_logf(1.0f + e) * 0.6931471805599453f;
}
__device__ __forceinline__ uint pk_h2(float a, float b) {
    return __builtin_bit_cast(uint, __builtin_amdgcn_cvt_pkrtz(a, b));
}

__global__ __launch_bounds__(512, 4)
void pm_kernel(const float* __restrict__ raw,        // (N,2,T)
               const float* __restrict__ in_proj_w,  // (8,2)
               const float* __restrict__ conv_w,     // (4,2)
               const float* __restrict__ conv_b,     // (4)
               const float* __restrict__ x_proj_w,   // (17,4)
               const float* __restrict__ dt_proj_w,  // (4,1)
               const float* __restrict__ dt_proj_b,  // (4)
               const float* __restrict__ A_log,      // (4,8)
               const float* __restrict__ D_skip,     // (4)
               const float* __restrict__ out_proj_w, // (2,4)
               const float* __restrict__ proj_w,     // (16,2)
               const float* __restrict__ proj_b,     // (16)
               float* __restrict__ out)              // (64,16), pre-zeroed
{
    __shared__ float lds[STAGE_TOTAL];

    const int tid  = threadIdx.x;
    const int wid  = tid >> 6;        // wave 0..7
    const int lane = tid & 63;
    const int half = lane >> 5;
    const int lh   = lane & 31;       // pointwise: t-in-chunk; scan: ds = d*8+s
    const int g    = wid * 2 + half;  // segment 0..15 of this block's sequence
    const int n    = blockIdx.x;      // one sequence per block
    const float* rp = raw + (size_t)n * (2 * TT);

    float* hb = lds + wid * PER_WAVE + half * PER_HALF_STRIDE;

    // ---- weights (wave-uniform -> scalarized) ----
    float ip0[8], ip1[8];
#pragma unroll
    for (int j = 0; j < 8; ++j) { ip0[j] = in_proj_w[2*j]; ip1[j] = in_proj_w[2*j+1]; }
    float dpw[4], dpb[4], Dsk[4], ow0[4], ow1[4], xp0[4];
    // conv folded into in_proj: v[d] = al*c0m + be*c1m + ga*c0 + de*c1 + cb
    v2f alp[2], bep[2], gap[2], dep[2], cbp[2], zc0[2], zc1[2];
#pragma unroll
    for (int d = 0; d < 4; ++d) {
        dpw[d] = dt_proj_w[d]; dpb[d] = dt_proj_b[d];
        Dsk[d] = D_skip[d]; ow0[d] = out_proj_w[d]; ow1[d] = out_proj_w[4+d];
        xp0[d] = x_proj_w[d];
    }
#pragma unroll
    for (int k = 0; k < 2; ++k) {
        int d0 = 2*k, d1 = 2*k + 1;
        float cw00 = conv_w[2*d0], cw01 = conv_w[2*d0+1];
        float cw10 = conv_w[2*d1], cw11 = conv_w[2*d1+1];
        alp[k] = (v2f){cw00*ip0[d0], cw10*ip0[d1]};
        bep[k] = (v2f){cw00*ip1[d0], cw10*ip1[d1]};
        gap[k] = (v2f){cw01*ip0[d0], cw11*ip0[d1]};
        dep[k] = (v2f){cw01*ip1[d0], cw11*ip1[d1]};
        cbp[k] = (v2f){conv_b[d0], conv_b[d1]};
        zc0[k] = (v2f){ip0[4+d0], ip0[4+d1]};
        zc1[k] = (v2f){ip1[4+d0], ip1[4+d1]};
    }
    v2f xbc[8][4];  // {x_proj_w[1+s][d], x_proj_w[9+s][d]}
#pragma unroll
    for (int s = 0; s < 8; ++s)
#pragma unroll
        for (int d = 0; d < 4; ++d)
            xbc[s][d] = (v2f){x_proj_w[4*(1+s) + d], x_proj_w[4*(9+s) + d]};

    const float LOG2E = 1.4426950408889634f;
    // scan-role constants: lane lh -> (d,s)
    const int   d_idx = lh >> 3;
    const int   s_idx = lh & 7;
    const float A2ds  = -__expf(A_log[lh]) * LOG2E;   // a = exp2(dt * A2ds)
    const float owd0  = out_proj_w[d_idx];
    const float owd1  = out_proj_w[4 + d_idx];

    // hoisted scan read pointers (imm offsets inside the loop)
    const float* dtp = hb + DT_OFF + d_idx;                  // [t2*4]
    const uint*  dsp = (const uint*)(hb + DS_OFF) + d_idx;   // [t2*4]
    const uint*  bcp = (const uint*)(hb + BC_OFF) + s_idx * BC_STRIDE; // [t2]

    // segment-local affine reduction state (per ds lane)
    float A_run = 1.0f, hB = 0.0f, W = 0.0f, S = 0.0f;
    float sacc0 = 0.f, sacc1 = 0.f;                    // skip-term partials

    const int seg0 = g * SEGLEN;

    // prefetch chunk 0 raw samples (t and t-1, both channels)
    int t0 = seg0 + lh;
    float c0  = rp[t0];
    float c1  = rp[TT + t0];
    float c0m = (t0 > 0) ? rp[t0 - 1]      : 0.0f;     // causal pad at t==0
    float c1m = (t0 > 0) ? rp[TT + t0 - 1] : 0.0f;

    for (int chunk = 0; chunk < NCHUNK; ++chunk) {
        // software prefetch next chunk's raw
        float p0 = 0.f, p1 = 0.f, p0m = 0.f, p1m = 0.f;
        if (chunk + 1 < NCHUNK) {
            int tn = seg0 + (chunk + 1) * TC + lh;     // tn >= 32 -> tn-1 valid
            p0  = rp[tn];       p1  = rp[TT + tn];
            p0m = rp[tn - 1];   p1m = rp[TT + tn - 1];
        }

        // ---- pointwise: this lane handles t = seg0 + chunk*TC + lh ----
        float x[4], sz[4];
        const v2f c0v = {c0, c0}, c1v = {c1, c1};
        const v2f c0mv = {c0m, c0m}, c1mv = {c1m, c1m};
#pragma unroll
        for (int k = 0; k < 2; ++k) {
            v2f v = __builtin_elementwise_fma(alp[k], c0mv,
                    __builtin_elementwise_fma(bep[k], c1mv,
                    __builtin_elementwise_fma(gap[k], c0v,
                    __builtin_elementwise_fma(dep[k], c1v, cbp[k]))));
            v2f zv = __builtin_elementwise_fma(zc0[k], c0v, zc1[k] * c1v);
            x[2*k]    = fast_silu(v.x);
            x[2*k+1]  = fast_silu(v.y);
            sz[2*k]   = fast_silu(zv.x);
            sz[2*k+1] = fast_silu(zv.y);
        }

        float dtin = xp0[0]*x[0] + xp0[1]*x[1] + xp0[2]*x[2] + xp0[3]*x[3];

        v2f bc[8];
#pragma unroll
        for (int s = 0; s < 8; ++s) {
            v2f a = xbc[s][0] * (v2f){x[0], x[0]};
            a = __builtin_elementwise_fma(xbc[s][1], (v2f){x[1], x[1]}, a);
            a = __builtin_elementwise_fma(xbc[s][2], (v2f){x[2], x[2]}, a);
            bc[s] = __builtin_elementwise_fma(xbc[s][3], (v2f){x[3], x[3]}, a);
        }

        float dt[4];
#pragma unroll
        for (int d = 0; d < 4; ++d) {
            dt[d] = fast_softplus(dtin*dpw[d] + dpb[d]);
            float g2 = x[d] * Dsk[d] * sz[d];              // skip term
            sacc0 = fmaf(g2, ow0[d], sacc0);
            sacc1 = fmaf(g2, ow1[d], sacc1);
        }

        // stage: DT (float4, lane-consecutive), DS (uint4), BC (8x b32)
        *(float4*)(hb + DT_OFF + lh*4) = make_float4(dt[0], dt[1], dt[2], dt[3]);
        *(uint4*)((uint*)(hb + DS_OFF) + lh*4) =
            make_uint4(pk_h2(dt[0]*x[0], sz[0]), pk_h2(dt[1]*x[1], sz[1]),
                       pk_h2(dt[2]*x[2], sz[2]), pk_h2(dt[3]*x[3], sz[3]));
        uint* bcw = (uint*)(hb + BC_OFF) + lh;
#pragma unroll
        for (int s = 0; s < 8; ++s)
            bcw[s * BC_STRIDE] = pk_h2(bc[s].x, bc[s].y);

        // ---- scan: lane owns (d_idx, s_idx); local affine reduction ----
        // (same-wave LDS RAW: compiler orders via its own waitcnt insertion)
#pragma unroll
        for (int t2 = 0; t2 < TC; ++t2) {
            float dtv = dtp[t2*4];                          // broadcast b32
            uint  uds = dsp[t2*4];                          // half2(dtx, sz)
            uint  ubc = bcp[t2];                            // half2(B, C)
            __half2 prod = __hmul2(__builtin_bit_cast(__half2, uds),
                                   __builtin_bit_cast(__half2, ubc));
            float b = __half2float(__low2half(prod));       // dtx*B
            float q = __half2float(__high2half(prod));      // sz*C
            float a = __builtin_amdgcn_exp2f(dtv * A2ds);
            A_run *= a;                    // running product  П a
            hB = fmaf(a, hB, b);           // local scan, h_in = 0
            W  = fmaf(A_run, q, W);        // h_in-coupling coefficient
            S  = fmaf(hB, q, S);           // h_in-independent contribution
        }

        c0 = p0; c1 = p1; c0m = p0m; c1m = p1m;
    }

    // ---- cross-segment combine (aliases dead staging LDS, post-barrier) ----
    __syncthreads();
    float2* comb = (float2*)lds;                       // 16*32 float2 = 1024 floats
    comb[g*32 + lh] = make_float2(A_run, hB);
    __syncthreads();

    // compose the segments before g to get this segment's h_in (g wave-uniform
    // per half; exec-masked loop, max 15 iters)
    float h_in = 0.0f;
#pragma unroll
    for (int gg = 0; gg < NSEGS - 1; ++gg) {
        if (gg < g) {
            float2 abg = comb[gg*32 + lh];
            h_in = fmaf(abg.x, h_in, abg.y);
        }
    }

    float F = fmaf(h_in, W, S);          // this segment's Σ_t h_t q_t for (d,s)
    float tot0 = fmaf(F, owd0, sacc0);
    float tot1 = fmaf(F, owd1, sacc1);
#pragma unroll
    for (int m = 16; m >= 1; m >>= 1) {  // reduce within the 32-lane half
        tot0 += __shfl_xor(tot0, m, 64);
        tot1 += __shfl_xor(tot1, m, 64);
    }
    float* part = lds + 1024;            // past comb region
    if (lh == 0) {
        part[g*2]     = tot0;
        part[g*2 + 1] = tot1;
    }
    __syncthreads();

    // first 16 threads: sum segment partials, head projection, mean over pairs
    if (tid < 16) {
        float f0 = 0.f, f1 = 0.f;
#pragma unroll
        for (int gg = 0; gg < NSEGS; ++gg) {
            f0 += part[gg*2];
            f1 += part[gg*2 + 1];
        }
        f0 *= (1.0f / (float)TT);
        f1 *= (1.0f / (float)TT);
        float pv = f0*proj_w[2*tid] + f1*proj_w[2*tid + 1] + proj_b[tid];
        pv = fmaxf(pv, 0.0f);
        atomicAdd(out + (n / NUM_PAIRS) * 16 + tid, pv * (1.0f / NUM_PAIRS));
    }
}

extern "C" void kernel_launch(void* const* d_in, const int* in_sizes, int n_in,
                              void* d_out, int out_size, void* d_ws, size_t ws_size,
                              hipStream_t stream)
{
    const float* raw        = (const float*)d_in[0];
    const float* in_proj_w  = (const float*)d_in[1];
    const float* conv_w     = (const float*)d_in[2];
    const float* conv_b     = (const float*)d_in[3];
    const float* x_proj_w   = (const float*)d_in[4];
    const float* dt_proj_w  = (const float*)d_in[5];
    const float* dt_proj_b  = (const float*)d_in[6];
    const float* A_log      = (const float*)d_in[7];
    const float* D_skip     = (const float*)d_in[8];
    const float* out_proj_w = (const float*)d_in[9];
    const float* proj_w     = (const float*)d_in[10];
    const float* proj_b     = (const float*)d_in[11];

    // d_out is re-poisoned before every timed replay; zero it (atomicAdd sink)
    hipMemsetAsync(d_out, 0, (size_t)out_size * sizeof(float), stream);

    pm_kernel<<<dim3(NSEQ), dim3(512), 0, stream>>>(
        raw, in_proj_w, conv_w, conv_b, x_proj_w, dt_proj_w, dt_proj_b,
        A_log, D_skip, out_proj_w, proj_w, proj_b, (float*)d_out);
}

// Round 9
// 118.681 us; speedup vs baseline: 1.0347x; 1.0347x over previous
//
#include <hip/hip_runtime.h>
#include <hip/hip_fp16.h>

// PairwiseMamba: 2304 independent mamba scans (T=1024, d_inner=4, d_state=8).
// R8: single-round residency. 192-thr blocks (3 waves), 1 seq/block, 6 ragged
// segments (chunks-of-32: 6,6,5,5,5,5; wave w's halves get equal trip counts
// -> wave-uniform loops). 12.7KB LDS, 32/3-wave cap -> 10 blocks/CU resident
// vs 9 supply: the entire 2304-block grid is co-resident, no 2-round tail
// (R6's 9-vs-8 overhang cost ~40%). launch_bounds(192,4) -> 64-VGPR budget,
// the proven no-spill regime (R6: 44 used; R7 at 8 waves hit 64 and spilled).
// Staging per (wave,half), all HW-coalesced contiguous writes (0 conflicts
// measured R4/R6): DT[t][d] float4, DS[t][d] uint4 half2(dtx,sz),
// BC[s][t] b32 stride 33; scan reads are b32 broadcasts on disjoint banks.
// Pointwise: conv folded into in_proj (R7, verified correct).

typedef float v2f __attribute__((ext_vector_type(2)));

#define TT 1024
#define TC 32
#define NSEGS 6
#define NUM_PAIRS 36
#define NSEQ 2304

// per-(wave,half) staging layout (float/uint slots):
// DT [0,128) floats, DS [128,256) uints, BC [256,520) uints
#define DT_OFF 0
#define DS_OFF 128
#define BC_OFF 256
#define BC_STRIDE 33                   // half2 slots per BC row (bank spread)
#define PER_HALF_STRIDE 528            // floats; %32==16 -> halves bank-disjoint
#define PER_WAVE (2 * PER_HALF_STRIDE) // 1056 floats
#define STAGE_TOTAL (3 * PER_WAVE)     // 3168 floats = 12672 B

__device__ __forceinline__ float fast_silu(float v) {
    float e = __builtin_amdgcn_exp2f(v * -1.4426950408889634f);
    return v * __builtin_amdgcn_rcpf(1.0f + e);
}
// softplus, direct form: log(1+exp(v)). Safe: |v| <~ 20 here.
__device__ __forceinline__ float fast_softplus(float v) {
    float e = __builtin_amdgcn_exp2f(v * 1.4426950408889634f);
    return __builtin_amdgcn_logf(1.0f + e) * 0.6931471805599453f;
}
__device__ __forceinline__ uint pk_h2(float a, float b) {
    return __builtin_bit_cast(uint, __builtin_amdgcn_cvt_pkrtz(a, b));
}

__global__ __launch_bounds__(192, 4)
void pm_kernel(const float* __restrict__ raw,        // (N,2,T)
               const float* __restrict__ in_proj_w,  // (8,2)
               const float* __restrict__ conv_w,     // (4,2)
               const float* __restrict__ conv_b,     // (4)
               const float* __restrict__ x_proj_w,   // (17,4)
               const float* __restrict__ dt_proj_w,  // (4,1)
               const float* __restrict__ dt_proj_b,  // (4)
               const float* __restrict__ A_log,      // (4,8)
               const float* __restrict__ D_skip,     // (4)
               const float* __restrict__ out_proj_w, // (2,4)
               const float* __restrict__ proj_w,     // (16,2)
               const float* __restrict__ proj_b,     // (16)
               float* __restrict__ out)              // (64,16), pre-zeroed
{
    __shared__ float lds[STAGE_TOTAL];

    const int tid  = threadIdx.x;
    const int wid  = tid >> 6;        // wave 0..2
    const int lane = tid & 63;
    const int half = lane >> 5;
    const int lh   = lane & 31;       // pointwise: t-in-chunk; scan: ds = d*8+s
    const int g    = wid * 2 + half;  // segment 0..5 of this block's sequence
    const int n    = blockIdx.x;      // one sequence per block
    const float* rp = raw + (size_t)n * (2 * TT);

    // ragged segments in chunks of 32: counts {6,6,5,5,5,5}, prefix {0,6,12,17,22,27}
    const int nch  = (g < 2) ? 6 : 5;                 // wave-uniform trip count
    const int seg0 = 32 * ((g < 2) ? 6 * g : 5 * g + 2);

    float* hb = lds + wid * PER_WAVE + half * PER_HALF_STRIDE;

    // ---- weights (wave-uniform -> scalarized) ----
    float ip0[8], ip1[8];
#pragma unroll
    for (int j = 0; j < 8; ++j) { ip0[j] = in_proj_w[2*j]; ip1[j] = in_proj_w[2*j+1]; }
    float dpw[4], dpb[4], Dsk[4], ow0[4], ow1[4], xp0[4];
    // conv folded into in_proj: v[d] = al*c0m + be*c1m + ga*c0 + de*c1 + cb
    v2f alp[2], bep[2], gap[2], dep[2], cbp[2], zc0[2], zc1[2];
#pragma unroll
    for (int d = 0; d < 4; ++d) {
        dpw[d] = dt_proj_w[d]; dpb[d] = dt_proj_b[d];
        Dsk[d] = D_skip[d]; ow0[d] = out_proj_w[d]; ow1[d] = out_proj_w[4+d];
        xp0[d] = x_proj_w[d];
    }
#pragma unroll
    for (int k = 0; k < 2; ++k) {
        int d0 = 2*k, d1 = 2*k + 1;
        float cw00 = conv_w[2*d0], cw01 = conv_w[2*d0+1];
        float cw10 = conv_w[2*d1], cw11 = conv_w[2*d1+1];
        alp[k] = (v2f){cw00*ip0[d0], cw10*ip0[d1]};
        bep[k] = (v2f){cw00*ip1[d0], cw10*ip1[d1]};
        gap[k] = (v2f){cw01*ip0[d0], cw11*ip0[d1]};
        dep[k] = (v2f){cw01*ip1[d0], cw11*ip1[d1]};
        cbp[k] = (v2f){conv_b[d0], conv_b[d1]};
        zc0[k] = (v2f){ip0[4+d0], ip0[4+d1]};
        zc1[k] = (v2f){ip1[4+d0], ip1[4+d1]};
    }
    v2f xbc[8][4];  // {x_proj_w[1+s][d], x_proj_w[9+s][d]}
#pragma unroll
    for (int s = 0; s < 8; ++s)
#pragma unroll
        for (int d = 0; d < 4; ++d)
            xbc[s][d] = (v2f){x_proj_w[4*(1+s) + d], x_proj_w[4*(9+s) + d]};

    const float LOG2E = 1.4426950408889634f;
    // scan-role constants: lane lh -> (d,s)
    const int   d_idx = lh >> 3;
    const int   s_idx = lh & 7;
    const float A2ds  = -__expf(A_log[lh]) * LOG2E;   // a = exp2(dt * A2ds)
    const float owd0  = out_proj_w[d_idx];
    const float owd1  = out_proj_w[4 + d_idx];

    // hoisted scan read pointers (imm offsets inside the loop)
    const float* dtp = hb + DT_OFF + d_idx;                  // [t2*4]
    const uint*  dsp = (const uint*)(hb + DS_OFF) + d_idx;   // [t2*4]
    const uint*  bcp = (const uint*)(hb + BC_OFF) + s_idx * BC_STRIDE; // [t2]

    // segment-local affine reduction state (per ds lane)
    float A_run = 1.0f, hB = 0.0f, W = 0.0f, S = 0.0f;
    float sacc0 = 0.f, sacc1 = 0.f;                    // skip-term partials

    // prefetch chunk 0 raw samples (t and t-1, both channels)
    int t0 = seg0 + lh;
    float c0  = rp[t0];
    float c1  = rp[TT + t0];
    float c0m = (t0 > 0) ? rp[t0 - 1]      : 0.0f;     // causal pad at t==0
    float c1m = (t0 > 0) ? rp[TT + t0 - 1] : 0.0f;

    for (int chunk = 0; chunk < nch; ++chunk) {
        // software prefetch next chunk's raw
        float p0 = 0.f, p1 = 0.f, p0m = 0.f, p1m = 0.f;
        if (chunk + 1 < nch) {
            int tn = seg0 + (chunk + 1) * TC + lh;     // tn >= 32 -> tn-1 valid
            p0  = rp[tn];       p1  = rp[TT + tn];
            p0m = rp[tn - 1];   p1m = rp[TT + tn - 1];
        }

        // ---- pointwise: this lane handles t = seg0 + chunk*TC + lh ----
        float x[4], sz[4];
        const v2f c0v = {c0, c0}, c1v = {c1, c1};
        const v2f c0mv = {c0m, c0m}, c1mv = {c1m, c1m};
#pragma unroll
        for (int k = 0; k < 2; ++k) {
            v2f v = __builtin_elementwise_fma(alp[k], c0mv,
                    __builtin_elementwise_fma(bep[k], c1mv,
                    __builtin_elementwise_fma(gap[k], c0v,
                    __builtin_elementwise_fma(dep[k], c1v, cbp[k]))));
            v2f zv = __builtin_elementwise_fma(zc0[k], c0v, zc1[k] * c1v);
            x[2*k]    = fast_silu(v.x);
            x[2*k+1]  = fast_silu(v.y);
            sz[2*k]   = fast_silu(zv.x);
            sz[2*k+1] = fast_silu(zv.y);
        }

        float dtin = xp0[0]*x[0] + xp0[1]*x[1] + xp0[2]*x[2] + xp0[3]*x[3];

        v2f bc[8];
#pragma unroll
        for (int s = 0; s < 8; ++s) {
            v2f a = xbc[s][0] * (v2f){x[0], x[0]};
            a = __builtin_elementwise_fma(xbc[s][1], (v2f){x[1], x[1]}, a);
            a = __builtin_elementwise_fma(xbc[s][2], (v2f){x[2], x[2]}, a);
            bc[s] = __builtin_elementwise_fma(xbc[s][3], (v2f){x[3], x[3]}, a);
        }

        float dt[4];
#pragma unroll
        for (int d = 0; d < 4; ++d) {
            dt[d] = fast_softplus(dtin*dpw[d] + dpb[d]);
            float g2 = x[d] * Dsk[d] * sz[d];              // skip term
            sacc0 = fmaf(g2, ow0[d], sacc0);
            sacc1 = fmaf(g2, ow1[d], sacc1);
        }

        // stage: DT (float4, lane-consecutive), DS (uint4), BC (8x b32)
        *(float4*)(hb + DT_OFF + lh*4) = make_float4(dt[0], dt[1], dt[2], dt[3]);
        *(uint4*)((uint*)(hb + DS_OFF) + lh*4) =
            make_uint4(pk_h2(dt[0]*x[0], sz[0]), pk_h2(dt[1]*x[1], sz[1]),
                       pk_h2(dt[2]*x[2], sz[2]), pk_h2(dt[3]*x[3], sz[3]));
        uint* bcw = (uint*)(hb + BC_OFF) + lh;
#pragma unroll
        for (int s = 0; s < 8; ++s)
            bcw[s * BC_STRIDE] = pk_h2(bc[s].x, bc[s].y);

        // ---- scan: lane owns (d_idx, s_idx); local affine reduction ----
        // (same-wave LDS RAW: compiler orders via its own waitcnt insertion)
#pragma unroll
        for (int t2 = 0; t2 < TC; ++t2) {
            float dtv = dtp[t2*4];                          // broadcast b32
            uint  uds = dsp[t2*4];                          // half2(dtx, sz)
            uint  ubc = bcp[t2];                            // half2(B, C)
            __half2 prod = __hmul2(__builtin_bit_cast(__half2, uds),
                                   __builtin_bit_cast(__half2, ubc));
            float b = __half2float(__low2half(prod));       // dtx*B
            float q = __half2float(__high2half(prod));      // sz*C
            float a = __builtin_amdgcn_exp2f(dtv * A2ds);
            A_run *= a;                    // running product  П a
            hB = fmaf(a, hB, b);           // local scan, h_in = 0
            W  = fmaf(A_run, q, W);        // h_in-coupling coefficient
            S  = fmaf(hB, q, S);           // h_in-independent contribution
        }

        c0 = p0; c1 = p1; c0m = p0m; c1m = p1m;
    }

    // ---- cross-segment combine (aliases dead staging LDS, post-barrier) ----
    __syncthreads();
    float2* comb = (float2*)lds;                       // 6*32 float2 = 384 floats
    comb[g*32 + lh] = make_float2(A_run, hB);
    __syncthreads();

    // compose the segments before g to get this segment's h_in
    float h_in = 0.0f;
#pragma unroll
    for (int gg = 0; gg < NSEGS - 1; ++gg) {
        if (gg < g) {
            float2 abg = comb[gg*32 + lh];
            h_in = fmaf(abg.x, h_in, abg.y);
        }
    }

    float F = fmaf(h_in, W, S);          // this segment's Σ_t h_t q_t for (d,s)
    float tot0 = fmaf(F, owd0, sacc0);
    float tot1 = fmaf(F, owd1, sacc1);
#pragma unroll
    for (int m = 16; m >= 1; m >>= 1) {  // reduce within the 32-lane half
        tot0 += __shfl_xor(tot0, m, 64);
        tot1 += __shfl_xor(tot1, m, 64);
    }
    float* part = lds + 512;             // past comb region
    if (lh == 0) {
        part[g*2]     = tot0;
        part[g*2 + 1] = tot1;
    }
    __syncthreads();

    // first 16 threads: sum segment partials, head projection, mean over pairs
    if (tid < 16) {
        float f0 = 0.f, f1 = 0.f;
#pragma unroll
        for (int gg = 0; gg < NSEGS; ++gg) {
            f0 += part[gg*2];
            f1 += part[gg*2 + 1];
        }
        f0 *= (1.0f / (float)TT);
        f1 *= (1.0f / (float)TT);
        float pv = f0*proj_w[2*tid] + f1*proj_w[2*tid + 1] + proj_b[tid];
        pv = fmaxf(pv, 0.0f);
        atomicAdd(out + (n / NUM_PAIRS) * 16 + tid, pv * (1.0f / NUM_PAIRS));
    }
}

extern "C" void kernel_launch(void* const* d_in, const int* in_sizes, int n_in,
                              void* d_out, int out_size, void* d_ws, size_t ws_size,
                              hipStream_t stream)
{
    const float* raw        = (const float*)d_in[0];
    const float* in_proj_w  = (const float*)d_in[1];
    const float* conv_w     = (const float*)d_in[2];
    const float* conv_b     = (const float*)d_in[3];
    const float* x_proj_w   = (const float*)d_in[4];
    const float* dt_proj_w  = (const float*)d_in[5];
    const float* dt_proj_b  = (const float*)d_in[6];
    const float* A_log      = (const float*)d_in[7];
    const float* D_skip     = (const float*)d_in[8];
    const float* out_proj_w = (const float*)d_in[9];
    const float* proj_w     = (const float*)d_in[10];
    const float* proj_b     = (const float*)d_in[11];

    // d_out is re-poisoned before every timed replay; zero it (atomicAdd sink)
    hipMemsetAsync(d_out, 0, (size_t)out_size * sizeof(float), stream);

    pm_kernel<<<dim3(NSEQ), dim3(192), 0, stream>>>(
        raw, in_proj_w, conv_w, conv_b, x_proj_w, dt_proj_w, dt_proj_b,
        A_log, D_skip, out_proj_w, proj_w, proj_b, (float*)d_out);
}